// Round 4
// baseline (1536.523 us; speedup 1.0000x reference)
//
#include <hip/hip_runtime.h>

#define N_NODES 100000
#define IN_CH 128
#define HID_CH 256
#define OUT_CH 128
#define N_EDGES 1600000

#define NBK 782                                   // ceil(N_NODES/128) buckets of 128 nodes
#define BIN_BLOCKS 256
#define EPB (N_EDGES / BIN_BLOCKS)                // 6250 edges per bin block

typedef __attribute__((ext_vector_type(8))) short short8;
typedef __attribute__((ext_vector_type(4))) float f32x4;

// bf16 <-> f32 helpers (bit ops; finite data only)
__device__ __forceinline__ float b2f(ushort u) {
    unsigned int x = ((unsigned int)u) << 16;
    return __uint_as_float(x);
}
__device__ __forceinline__ ushort f2b(float f) {
    unsigned int u = __float_as_uint(f);
    u += 0x7FFFu + ((u >> 16) & 1u);   // round-to-nearest-even
    return (ushort)(u >> 16);
}

// ---------------------------------------------------------------------------
// Prep: x fp32 -> xb bf16 ; W1 [128][256] -> W1T bf16 [256][128] ;
//       W2 [256][128] -> W2T bf16 [128][256]
// ---------------------------------------------------------------------------
#define PREP_X_BLOCKS 6250
#define PREP_W1_BLOCKS 128
#define PREP_W2_BLOCKS 128
__global__ __launch_bounds__(256) void prep_kernel(
    const float* __restrict__ x, const float* __restrict__ W1,
    const float* __restrict__ W2,
    ushort* __restrict__ xb, ushort* __restrict__ W1T,
    ushort* __restrict__ W2T) {
    const int b = blockIdx.x;
    const int t = threadIdx.x;
    if (b < PREP_X_BLOCKS) {
        const size_t i = (size_t)b * 2048 + t * 8;
        float4 a = *reinterpret_cast<const float4*>(x + i);
        float4 c = *reinterpret_cast<const float4*>(x + i + 4);
        ushort v[8] = {f2b(a.x), f2b(a.y), f2b(a.z), f2b(a.w),
                       f2b(c.x), f2b(c.y), f2b(c.z), f2b(c.w)};
        *reinterpret_cast<short8*>(xb + i) = *reinterpret_cast<short8*>(v);
    } else if (b < PREP_X_BLOCKS + PREP_W1_BLOCKS) {
        const int i = (b - PREP_X_BLOCKS) * 256 + t;     // oc*128 + k
        const int oc = i >> 7, k = i & 127;
        W1T[i] = f2b(W1[k * HID_CH + oc]);
    } else {
        const int i = (b - PREP_X_BLOCKS - PREP_W1_BLOCKS) * 256 + t; // oc*256+k
        const int oc = i >> 8, k = i & 255;
        W2T[i] = f2b(W2[k * OUT_CH + oc]);
    }
}

// ---------------------------------------------------------------------------
// Bucketing step 1: per-(block,bucket) histogram (LDS), transposed store.
// ---------------------------------------------------------------------------
__global__ __launch_bounds__(256) void ghist_kernel(
    const int* __restrict__ dst, int* __restrict__ histT) {
    __shared__ int h[NBK];
    const int b = blockIdx.x, t = threadIdx.x;
    for (int k = t; k < NBK; k += 256) h[k] = 0;
    __syncthreads();
    const int base = b * EPB;
    for (int i = t; i < EPB; i += 256)
        atomicAdd(&h[dst[base + i] >> 7], 1);
    __syncthreads();
    for (int k = t; k < NBK; k += 256) histT[k * BIN_BLOCKS + b] = h[k];
}

// ---------------------------------------------------------------------------
// Bucketing step 2a: per-bucket exclusive scan over the 256 block counts.
// ---------------------------------------------------------------------------
__global__ __launch_bounds__(256) void scanA_kernel(
    const int* __restrict__ histT, int* __restrict__ blockBaseP,
    int* __restrict__ bktTotal) {
    __shared__ int ts[256];
    const int bk = blockIdx.x, t = threadIdx.x;
    const int v = histT[bk * BIN_BLOCKS + t];
    ts[t] = v;
    __syncthreads();
    #pragma unroll
    for (int o = 1; o < 256; o <<= 1) {
        int add = (t >= o) ? ts[t - o] : 0;
        __syncthreads();
        ts[t] += add;
        __syncthreads();
    }
    blockBaseP[bk * BIN_BLOCKS + t] = ts[t] - v;
    if (t == 255) bktTotal[bk] = ts[255];
}

// ---------------------------------------------------------------------------
// Bucketing step 2b: exclusive scan of the 782 bucket totals (1 block).
// ---------------------------------------------------------------------------
__global__ __launch_bounds__(1024) void scanB_kernel(
    const int* __restrict__ bktTotal, int* __restrict__ bktBase) {
    __shared__ int ts[1024];
    const int t = threadIdx.x;
    const int v = (t < NBK) ? bktTotal[t] : 0;
    ts[t] = v;
    __syncthreads();
    #pragma unroll
    for (int o = 1; o < 1024; o <<= 1) {
        int add = (t >= o) ? ts[t - o] : 0;
        __syncthreads();
        ts[t] += add;
        __syncthreads();
    }
    if (t < NBK) bktBase[t] = ts[t] - v;
}

// ---------------------------------------------------------------------------
// Bucketing step 3: scatter packed entries (dl<<17 | src) into per-block
// contiguous runs inside each bucket region. No contended global atomics.
// ---------------------------------------------------------------------------
__global__ __launch_bounds__(256) void bin_kernel(
    const int* __restrict__ src, const int* __restrict__ dst,
    const int* __restrict__ blockBaseP, const int* __restrict__ bktBase,
    unsigned int* __restrict__ ebuf) {
    __shared__ int base[NBK];
    __shared__ int cur[NBK];
    const int b = blockIdx.x, t = threadIdx.x;
    for (int k = t; k < NBK; k += 256) {
        base[k] = bktBase[k] + blockBaseP[k * BIN_BLOCKS + b];
        cur[k] = 0;
    }
    __syncthreads();
    const int ebase = b * EPB;
    for (int i = t; i < EPB; i += 256) {
        const int d = dst[ebase + i];
        const int s = src[ebase + i];
        const int bk = d >> 7;
        const int r = atomicAdd(&cur[bk], 1);
        ebuf[base[bk] + r] = ((unsigned int)(d & 127) << 17) | (unsigned int)s;
    }
}

// ---------------------------------------------------------------------------
// Aggregate: one block per bucket; fp32 accumulators [128 nodes][128 ch] in
// LDS (64 KB). Half-wave per edge: lane c owns channels {c,c+32,c+64,c+96}
// -> coalesced 64B xb reads, bank-conflict-free ds_add_f32.
// Fuses (1+eps)*x self-term and bf16 convert:  h_in = bf16((1+eps)x + aggr).
// ---------------------------------------------------------------------------
__global__ __launch_bounds__(256) void aggregate_kernel(
    const ushort* __restrict__ xb,
    const float* __restrict__ eps_p,
    const unsigned int* __restrict__ ebuf,
    const int* __restrict__ bktBase, const int* __restrict__ bktTotal,
    ushort* __restrict__ h_in) {
    __shared__ float aggr[128 * 128];    // 64 KB
    __shared__ unsigned int q[256];
    const int bk = blockIdx.x, t = threadIdx.x;

    f32x4* a4 = reinterpret_cast<f32x4*>(aggr);
    #pragma unroll
    for (int i = 0; i < 16; ++i) a4[t + 256 * i] = (f32x4){0.f, 0.f, 0.f, 0.f};
    __syncthreads();

    const int start = bktBase[bk];
    const int cnt   = bktTotal[bk];
    const int hw = t >> 5, c = t & 31;

    for (int tile = 0; tile < cnt; tile += 256) {
        const int n = min(256, cnt - tile);
        if (t < n) q[t] = ebuf[start + tile + t];
        __syncthreads();
        for (int i = hw; i < n; i += 8) {
            const unsigned int e = q[i];
            const int s  = e & 0x1FFFF;
            const int dl = e >> 17;
            const ushort* xr = xb + (size_t)s * IN_CH + c;
            float* ar = aggr + dl * IN_CH + c;
            atomicAdd(ar + 0,  b2f(xr[0]));
            atomicAdd(ar + 32, b2f(xr[32]));
            atomicAdd(ar + 64, b2f(xr[64]));
            atomicAdd(ar + 96, b2f(xr[96]));
        }
        __syncthreads();
    }

    const float scale = 1.0f + eps_p[0];
    const int dl = t >> 1, hf = t & 1;
    const int node = bk * 128 + dl;
    if (node < N_NODES) {
        const int ch0 = hf * 64;
        #pragma unroll
        for (int k = 0; k < 16; ++k) {
            const int ch = ch0 + k * 4;
            float4 a = *reinterpret_cast<float4*>(aggr + dl * 128 + ch);
            ushort4 sv = *reinterpret_cast<const ushort4*>(
                xb + (size_t)node * IN_CH + ch);
            ushort4 o;
            o.x = f2b(scale * b2f(sv.x) + a.x);
            o.y = f2b(scale * b2f(sv.y) + a.y);
            o.z = f2b(scale * b2f(sv.z) + a.z);
            o.w = f2b(scale * b2f(sv.w) + a.w);
            *reinterpret_cast<ushort4*>(h_in + (size_t)node * IN_CH + ch) = o;
        }
    }
}

// ---------------------------------------------------------------------------
// GEMM1 (MFMA): h1 = bf16(relu(h_in @ W1 + b1))   [N,128]@[128,256] -> [N,256]
// ---------------------------------------------------------------------------
__global__ __launch_bounds__(256) void gemm1_mfma(
    const ushort* __restrict__ h_in,
    const ushort* __restrict__ W1T,
    const float* __restrict__ b1,
    ushort* __restrict__ h1) {
    const int w    = threadIdx.x >> 6;
    const int lane = threadIdx.x & 63;
    const int lr   = lane & 15;
    const int lk   = lane >> 4;
    const int arow = blockIdx.x * 64 + w * 16 + lr;
    const int arc  = arow < N_NODES ? arow : N_NODES - 1;

    short8 a[4];
    const ushort* ap = h_in + (size_t)arc * IN_CH + lk * 8;
    #pragma unroll
    for (int kk = 0; kk < 4; ++kk)
        a[kk] = *reinterpret_cast<const short8*>(ap + kk * 32);

    f32x4 acc[16];
    #pragma unroll
    for (int ct = 0; ct < 16; ++ct) acc[ct] = (f32x4){0.f, 0.f, 0.f, 0.f};

    #pragma unroll
    for (int ct = 0; ct < 16; ++ct) {
        const ushort* bp = W1T + (size_t)(ct * 16 + lr) * IN_CH + lk * 8;
        #pragma unroll
        for (int kk = 0; kk < 4; ++kk) {
            short8 b = *reinterpret_cast<const short8*>(bp + kk * 32);
            acc[ct] = __builtin_amdgcn_mfma_f32_16x16x32_bf16(a[kk], b, acc[ct], 0, 0, 0);
        }
    }

    const int orow0 = blockIdx.x * 64 + w * 16 + lk * 4;
    #pragma unroll
    for (int ct = 0; ct < 16; ++ct) {
        const int col = ct * 16 + lr;
        const float bb = b1[col];
        #pragma unroll
        for (int r = 0; r < 4; ++r) {
            const int orow = orow0 + r;
            if (orow < N_NODES) {
                float v = fmaxf(acc[ct][r] + bb, 0.0f);
                h1[(size_t)orow * HID_CH + col] = f2b(v);
            }
        }
    }
}

// ---------------------------------------------------------------------------
// GEMM2 (MFMA) + fused bias/relu/log_softmax -> fp32 out
// ---------------------------------------------------------------------------
__global__ __launch_bounds__(256) void gemm2_mfma(
    const ushort* __restrict__ h1,
    const ushort* __restrict__ W2T,
    const float* __restrict__ b2,
    float* __restrict__ out) {
    const int w    = threadIdx.x >> 6;
    const int lane = threadIdx.x & 63;
    const int lr   = lane & 15;
    const int lk   = lane >> 4;
    const int arow = blockIdx.x * 64 + w * 16 + lr;
    const int arc  = arow < N_NODES ? arow : N_NODES - 1;

    short8 a[8];
    const ushort* ap = h1 + (size_t)arc * HID_CH + lk * 8;
    #pragma unroll
    for (int kk = 0; kk < 8; ++kk)
        a[kk] = *reinterpret_cast<const short8*>(ap + kk * 32);

    f32x4 acc[8];
    #pragma unroll
    for (int ct = 0; ct < 8; ++ct) acc[ct] = (f32x4){0.f, 0.f, 0.f, 0.f};

    #pragma unroll
    for (int ct = 0; ct < 8; ++ct) {
        const ushort* bp = W2T + (size_t)(ct * 16 + lr) * HID_CH + lk * 8;
        #pragma unroll
        for (int kk = 0; kk < 8; ++kk) {
            short8 b = *reinterpret_cast<const short8*>(bp + kk * 32);
            acc[ct] = __builtin_amdgcn_mfma_f32_16x16x32_bf16(a[kk], b, acc[ct], 0, 0, 0);
        }
    }

    float bias[8];
    #pragma unroll
    for (int ct = 0; ct < 8; ++ct) bias[ct] = b2[ct * 16 + lr];

    const int orow0 = blockIdx.x * 64 + w * 16 + lk * 4;
    #pragma unroll
    for (int r = 0; r < 4; ++r) {
        float v[8];
        float m = -1e30f;
        #pragma unroll
        for (int ct = 0; ct < 8; ++ct) {
            v[ct] = fmaxf(acc[ct][r] + bias[ct], 0.0f);
            m = fmaxf(m, v[ct]);
        }
        #pragma unroll
        for (int o = 1; o < 16; o <<= 1) m = fmaxf(m, __shfl_xor(m, o));
        float s = 0.0f;
        #pragma unroll
        for (int ct = 0; ct < 8; ++ct) s += __expf(v[ct] - m);
        #pragma unroll
        for (int o = 1; o < 16; o <<= 1) s += __shfl_xor(s, o);
        const float lse = m + __logf(s);
        const int orow = orow0 + r;
        if (orow < N_NODES) {
            #pragma unroll
            for (int ct = 0; ct < 8; ++ct)
                out[(size_t)orow * OUT_CH + ct * 16 + lr] = v[ct] - lse;
        }
    }
}

extern "C" void kernel_launch(void* const* d_in, const int* in_sizes, int n_in,
                              void* d_out, int out_size, void* d_ws, size_t ws_size,
                              hipStream_t stream) {
    const float* x    = (const float*)d_in[0];
    const int*   ei   = (const int*)d_in[1];
    const float* W1   = (const float*)d_in[2];
    const float* b1   = (const float*)d_in[3];
    const float* W2   = (const float*)d_in[4];
    const float* b2   = (const float*)d_in[5];
    const float* eps  = (const float*)d_in[6];
    float* out = (float*)d_out;

    // workspace layout
    ushort* xb   = (ushort*)d_ws;                          // 12.8M ushort
    ushort* h_in = xb + (size_t)N_NODES * IN_CH;           // 12.8M
    ushort* h1   = h_in + (size_t)N_NODES * IN_CH;         // 25.6M
    ushort* W1T  = h1 + (size_t)N_NODES * HID_CH;          // 32768
    ushort* W2T  = W1T + IN_CH * HID_CH;                   // 32768
    int* histT      = (int*)(W2T + HID_CH * OUT_CH);       // NBK*256
    int* blockBaseP = histT + NBK * BIN_BLOCKS;            // NBK*256
    int* bktTotal   = blockBaseP + NBK * BIN_BLOCKS;       // NBK
    int* bktBase    = bktTotal + NBK;                      // NBK
    unsigned int* ebuf = (unsigned int*)(bktBase + NBK);   // 1.6M

    const int* src = ei;
    const int* dst = ei + N_EDGES;

    prep_kernel<<<PREP_X_BLOCKS + PREP_W1_BLOCKS + PREP_W2_BLOCKS, 256, 0, stream>>>(
        x, W1, W2, xb, W1T, W2T);
    ghist_kernel<<<BIN_BLOCKS, 256, 0, stream>>>(dst, histT);
    scanA_kernel<<<NBK, 256, 0, stream>>>(histT, blockBaseP, bktTotal);
    scanB_kernel<<<1, 1024, 0, stream>>>(bktTotal, bktBase);
    bin_kernel<<<BIN_BLOCKS, 256, 0, stream>>>(src, dst, blockBaseP, bktBase, ebuf);
    aggregate_kernel<<<NBK, 256, 0, stream>>>(xb, eps, ebuf, bktBase, bktTotal, h_in);

    gemm1_mfma<<<(N_NODES + 63) / 64, 256, 0, stream>>>(h_in, W1T, b1, h1);
    gemm2_mfma<<<(N_NODES + 63) / 64, 256, 0, stream>>>(h1, W2T, b2, out);
}

// Round 5
// 294.185 us; speedup vs baseline: 5.2230x; 5.2230x over previous
//
#include <hip/hip_runtime.h>

#define N_NODES 100000
#define IN_CH 128
#define HID_CH 256
#define OUT_CH 128
#define N_EDGES 1600000

#define NBK 782                                   // ceil(N_NODES/128) buckets of 128 nodes
#define BIN_BLOCKS 256
#define EPB (N_EDGES / BIN_BLOCKS)                // 6250 edges per bin block

typedef __attribute__((ext_vector_type(8))) short short8;
typedef __attribute__((ext_vector_type(4))) float f32x4;

// bf16 <-> f32 helpers (bit ops; finite data only)
__device__ __forceinline__ float b2f(ushort u) {
    unsigned int x = ((unsigned int)u) << 16;
    return __uint_as_float(x);
}
__device__ __forceinline__ ushort f2b(float f) {
    unsigned int u = __float_as_uint(f);
    u += 0x7FFFu + ((u >> 16) & 1u);   // round-to-nearest-even
    return (ushort)(u >> 16);
}

// ---------------------------------------------------------------------------
// Prep: x fp32 -> xb bf16 ; W1 [128][256] -> W1T bf16 [256][128] ;
//       W2 [256][128] -> W2T bf16 [128][256]
// ---------------------------------------------------------------------------
#define PREP_X_BLOCKS 6250
#define PREP_W1_BLOCKS 128
#define PREP_W2_BLOCKS 128
__global__ __launch_bounds__(256) void prep_kernel(
    const float* __restrict__ x, const float* __restrict__ W1,
    const float* __restrict__ W2,
    ushort* __restrict__ xb, ushort* __restrict__ W1T,
    ushort* __restrict__ W2T) {
    const int b = blockIdx.x;
    const int t = threadIdx.x;
    if (b < PREP_X_BLOCKS) {
        const size_t i = (size_t)b * 2048 + t * 8;
        float4 a = *reinterpret_cast<const float4*>(x + i);
        float4 c = *reinterpret_cast<const float4*>(x + i + 4);
        ushort v[8] = {f2b(a.x), f2b(a.y), f2b(a.z), f2b(a.w),
                       f2b(c.x), f2b(c.y), f2b(c.z), f2b(c.w)};
        *reinterpret_cast<short8*>(xb + i) = *reinterpret_cast<short8*>(v);
    } else if (b < PREP_X_BLOCKS + PREP_W1_BLOCKS) {
        const int i = (b - PREP_X_BLOCKS) * 256 + t;     // oc*128 + k
        const int oc = i >> 7, k = i & 127;
        W1T[i] = f2b(W1[k * HID_CH + oc]);
    } else {
        const int i = (b - PREP_X_BLOCKS - PREP_W1_BLOCKS) * 256 + t; // oc*256+k
        const int oc = i >> 8, k = i & 255;
        W2T[i] = f2b(W2[k * OUT_CH + oc]);
    }
}

// ---------------------------------------------------------------------------
// Bucketing step 1: per-(block,bucket) histogram (LDS), transposed store.
// ---------------------------------------------------------------------------
__global__ __launch_bounds__(256) void ghist_kernel(
    const int* __restrict__ dst, int* __restrict__ histT) {
    __shared__ int h[NBK];
    const int b = blockIdx.x, t = threadIdx.x;
    for (int k = t; k < NBK; k += 256) h[k] = 0;
    __syncthreads();
    const int base = b * EPB;
    for (int i = t; i < EPB; i += 256)
        atomicAdd(&h[dst[base + i] >> 7], 1);
    __syncthreads();
    for (int k = t; k < NBK; k += 256) histT[k * BIN_BLOCKS + b] = h[k];
}

// ---------------------------------------------------------------------------
// Bucketing step 2a: per-bucket exclusive scan over the 256 block counts.
// ---------------------------------------------------------------------------
__global__ __launch_bounds__(256) void scanA_kernel(
    const int* __restrict__ histT, int* __restrict__ blockBaseP,
    int* __restrict__ bktTotal) {
    __shared__ int ts[256];
    const int bk = blockIdx.x, t = threadIdx.x;
    const int v = histT[bk * BIN_BLOCKS + t];
    ts[t] = v;
    __syncthreads();
    #pragma unroll
    for (int o = 1; o < 256; o <<= 1) {
        int add = (t >= o) ? ts[t - o] : 0;
        __syncthreads();
        ts[t] += add;
        __syncthreads();
    }
    blockBaseP[bk * BIN_BLOCKS + t] = ts[t] - v;
    if (t == 255) bktTotal[bk] = ts[255];
}

// ---------------------------------------------------------------------------
// Bucketing step 2b: exclusive scan of the 782 bucket totals (1 block).
// ---------------------------------------------------------------------------
__global__ __launch_bounds__(1024) void scanB_kernel(
    const int* __restrict__ bktTotal, int* __restrict__ bktBase) {
    __shared__ int ts[1024];
    const int t = threadIdx.x;
    const int v = (t < NBK) ? bktTotal[t] : 0;
    ts[t] = v;
    __syncthreads();
    #pragma unroll
    for (int o = 1; o < 1024; o <<= 1) {
        int add = (t >= o) ? ts[t - o] : 0;
        __syncthreads();
        ts[t] += add;
        __syncthreads();
    }
    if (t < NBK) bktBase[t] = ts[t] - v;
}

// ---------------------------------------------------------------------------
// Bucketing step 3: scatter packed entries (dl<<17 | src) into per-block
// contiguous runs inside each bucket region. LDS cursors only.
// ---------------------------------------------------------------------------
__global__ __launch_bounds__(256) void bin_kernel(
    const int* __restrict__ src, const int* __restrict__ dst,
    const int* __restrict__ blockBaseP, const int* __restrict__ bktBase,
    unsigned int* __restrict__ ebuf) {
    __shared__ int base[NBK];
    __shared__ int cur[NBK];
    const int b = blockIdx.x, t = threadIdx.x;
    for (int k = t; k < NBK; k += 256) {
        base[k] = bktBase[k] + blockBaseP[k * BIN_BLOCKS + b];
        cur[k] = 0;
    }
    __syncthreads();
    const int ebase = b * EPB;
    for (int i = t; i < EPB; i += 256) {
        const int d = dst[ebase + i];
        const int s = src[ebase + i];
        const int bk = d >> 7;
        const int r = atomicAdd(&cur[bk], 1);
        ebuf[base[bk] + r] = ((unsigned int)(d & 127) << 17) | (unsigned int)s;
    }
}

// ---------------------------------------------------------------------------
// Bucketing step 4: node-sort each bucket -> exact CSR.
// Per bucket: LDS 128-bin hist -> scan -> scatter csr_src into the bucket's
// contiguous region (8 KB window, L2-merged). Also writes offs[node].
// ---------------------------------------------------------------------------
__global__ __launch_bounds__(256) void group_kernel(
    const unsigned int* __restrict__ ebuf,
    const int* __restrict__ bktBase, const int* __restrict__ bktTotal,
    int* __restrict__ csr_src, int* __restrict__ offs) {
    __shared__ int hist[128];
    __shared__ int cur[128];
    const int bk = blockIdx.x, t = threadIdx.x;
    if (t < 128) hist[t] = 0;
    __syncthreads();
    const int start = bktBase[bk];
    const int cnt   = bktTotal[bk];
    for (int i = t; i < cnt; i += 256)
        atomicAdd(&hist[ebuf[start + i] >> 17], 1);
    __syncthreads();
    // exclusive scan of hist[128] (Hillis-Steele, block-wide barriers)
    int v = (t < 128) ? hist[t] : 0;
    #pragma unroll
    for (int o = 1; o < 128; o <<= 1) {
        int add = (t < 128 && t >= o) ? hist[t - o] : 0;
        __syncthreads();
        if (t < 128) hist[t] += add;
        __syncthreads();
    }
    if (t < 128) {
        const int excl = hist[t] - v;
        cur[t] = excl;
        const int node = bk * 128 + t;
        if (node < N_NODES) offs[node] = start + excl;
    }
    if (bk == 0 && t == 0) offs[N_NODES] = N_EDGES;
    __syncthreads();
    for (int i = t; i < cnt; i += 256) {
        const unsigned int e = ebuf[start + i];
        const int dl = e >> 17;
        const int p = atomicAdd(&cur[dl], 1);
        csr_src[start + p] = (int)(e & 0x1FFFF);
    }
}

// ---------------------------------------------------------------------------
// Gather-aggregate fused with GIN self-term (bf16 rows, fp32 accum):
//   h_in[i] = bf16( (1+eps)*x[i] + sum_{j in N(i)} x[j] )
// 8 nodes/block, 32 threads/node, ushort4 (8 B) per thread = 256 B row.
// ---------------------------------------------------------------------------
__global__ __launch_bounds__(256) void gather_kernel(
    const ushort* __restrict__ xb,
    const float* __restrict__ eps_p,
    const int* __restrict__ offs,
    const int* __restrict__ csr_src,
    ushort* __restrict__ h_in) {
    const int node = blockIdx.x * 8 + (threadIdx.x >> 5);
    const int c = (threadIdx.x & 31) * 4;
    const int beg = offs[node];
    const int end = offs[node + 1];
    float a0 = 0.f, a1 = 0.f, a2 = 0.f, a3 = 0.f;
    for (int e = beg; e < end; ++e) {
        const int s = csr_src[e];
        ushort4 vv = *reinterpret_cast<const ushort4*>(xb + (size_t)s * IN_CH + c);
        a0 += b2f(vv.x); a1 += b2f(vv.y); a2 += b2f(vv.z); a3 += b2f(vv.w);
    }
    const float scale = 1.0f + eps_p[0];
    ushort4 sv = *reinterpret_cast<const ushort4*>(xb + (size_t)node * IN_CH + c);
    ushort4 o;
    o.x = f2b(scale * b2f(sv.x) + a0);
    o.y = f2b(scale * b2f(sv.y) + a1);
    o.z = f2b(scale * b2f(sv.z) + a2);
    o.w = f2b(scale * b2f(sv.w) + a3);
    *reinterpret_cast<ushort4*>(h_in + (size_t)node * IN_CH + c) = o;
}

// ---------------------------------------------------------------------------
// GEMM1 (MFMA): h1 = bf16(relu(h_in @ W1 + b1))   [N,128]@[128,256] -> [N,256]
// ---------------------------------------------------------------------------
__global__ __launch_bounds__(256) void gemm1_mfma(
    const ushort* __restrict__ h_in,
    const ushort* __restrict__ W1T,
    const float* __restrict__ b1,
    ushort* __restrict__ h1) {
    const int w    = threadIdx.x >> 6;
    const int lane = threadIdx.x & 63;
    const int lr   = lane & 15;
    const int lk   = lane >> 4;
    const int arow = blockIdx.x * 64 + w * 16 + lr;
    const int arc  = arow < N_NODES ? arow : N_NODES - 1;

    short8 a[4];
    const ushort* ap = h_in + (size_t)arc * IN_CH + lk * 8;
    #pragma unroll
    for (int kk = 0; kk < 4; ++kk)
        a[kk] = *reinterpret_cast<const short8*>(ap + kk * 32);

    f32x4 acc[16];
    #pragma unroll
    for (int ct = 0; ct < 16; ++ct) acc[ct] = (f32x4){0.f, 0.f, 0.f, 0.f};

    #pragma unroll
    for (int ct = 0; ct < 16; ++ct) {
        const ushort* bp = W1T + (size_t)(ct * 16 + lr) * IN_CH + lk * 8;
        #pragma unroll
        for (int kk = 0; kk < 4; ++kk) {
            short8 b = *reinterpret_cast<const short8*>(bp + kk * 32);
            acc[ct] = __builtin_amdgcn_mfma_f32_16x16x32_bf16(a[kk], b, acc[ct], 0, 0, 0);
        }
    }

    const int orow0 = blockIdx.x * 64 + w * 16 + lk * 4;
    #pragma unroll
    for (int ct = 0; ct < 16; ++ct) {
        const int col = ct * 16 + lr;
        const float bb = b1[col];
        #pragma unroll
        for (int r = 0; r < 4; ++r) {
            const int orow = orow0 + r;
            if (orow < N_NODES) {
                float v = fmaxf(acc[ct][r] + bb, 0.0f);
                h1[(size_t)orow * HID_CH + col] = f2b(v);
            }
        }
    }
}

// ---------------------------------------------------------------------------
// GEMM2 (MFMA) + fused bias/relu/log_softmax -> fp32 out
// ---------------------------------------------------------------------------
__global__ __launch_bounds__(256) void gemm2_mfma(
    const ushort* __restrict__ h1,
    const ushort* __restrict__ W2T,
    const float* __restrict__ b2,
    float* __restrict__ out) {
    const int w    = threadIdx.x >> 6;
    const int lane = threadIdx.x & 63;
    const int lr   = lane & 15;
    const int lk   = lane >> 4;
    const int arow = blockIdx.x * 64 + w * 16 + lr;
    const int arc  = arow < N_NODES ? arow : N_NODES - 1;

    short8 a[8];
    const ushort* ap = h1 + (size_t)arc * HID_CH + lk * 8;
    #pragma unroll
    for (int kk = 0; kk < 8; ++kk)
        a[kk] = *reinterpret_cast<const short8*>(ap + kk * 32);

    f32x4 acc[8];
    #pragma unroll
    for (int ct = 0; ct < 8; ++ct) acc[ct] = (f32x4){0.f, 0.f, 0.f, 0.f};

    #pragma unroll
    for (int ct = 0; ct < 8; ++ct) {
        const ushort* bp = W2T + (size_t)(ct * 16 + lr) * HID_CH + lk * 8;
        #pragma unroll
        for (int kk = 0; kk < 8; ++kk) {
            short8 b = *reinterpret_cast<const short8*>(bp + kk * 32);
            acc[ct] = __builtin_amdgcn_mfma_f32_16x16x32_bf16(a[kk], b, acc[ct], 0, 0, 0);
        }
    }

    float bias[8];
    #pragma unroll
    for (int ct = 0; ct < 8; ++ct) bias[ct] = b2[ct * 16 + lr];

    const int orow0 = blockIdx.x * 64 + w * 16 + lk * 4;
    #pragma unroll
    for (int r = 0; r < 4; ++r) {
        float v[8];
        float m = -1e30f;
        #pragma unroll
        for (int ct = 0; ct < 8; ++ct) {
            v[ct] = fmaxf(acc[ct][r] + bias[ct], 0.0f);
            m = fmaxf(m, v[ct]);
        }
        #pragma unroll
        for (int o = 1; o < 16; o <<= 1) m = fmaxf(m, __shfl_xor(m, o));
        float s = 0.0f;
        #pragma unroll
        for (int ct = 0; ct < 8; ++ct) s += __expf(v[ct] - m);
        #pragma unroll
        for (int o = 1; o < 16; o <<= 1) s += __shfl_xor(s, o);
        const float lse = m + __logf(s);
        const int orow = orow0 + r;
        if (orow < N_NODES) {
            #pragma unroll
            for (int ct = 0; ct < 8; ++ct)
                out[(size_t)orow * OUT_CH + ct * 16 + lr] = v[ct] - lse;
        }
    }
}

extern "C" void kernel_launch(void* const* d_in, const int* in_sizes, int n_in,
                              void* d_out, int out_size, void* d_ws, size_t ws_size,
                              hipStream_t stream) {
    const float* x    = (const float*)d_in[0];
    const int*   ei   = (const int*)d_in[1];
    const float* W1   = (const float*)d_in[2];
    const float* b1   = (const float*)d_in[3];
    const float* W2   = (const float*)d_in[4];
    const float* b2   = (const float*)d_in[5];
    const float* eps  = (const float*)d_in[6];
    float* out = (float*)d_out;

    // workspace layout
    ushort* xb   = (ushort*)d_ws;                          // 12.8M ushort
    ushort* h_in = xb + (size_t)N_NODES * IN_CH;           // 12.8M
    ushort* h1   = h_in + (size_t)N_NODES * IN_CH;         // 25.6M
    ushort* W1T  = h1 + (size_t)N_NODES * HID_CH;          // 32768
    ushort* W2T  = W1T + IN_CH * HID_CH;                   // 32768
    int* histT      = (int*)(W2T + HID_CH * OUT_CH);       // NBK*256
    int* blockBaseP = histT + NBK * BIN_BLOCKS;            // NBK*256
    int* bktTotal   = blockBaseP + NBK * BIN_BLOCKS;       // NBK
    int* bktBase    = bktTotal + NBK;                      // NBK
    int* offs       = bktBase + NBK;                       // N_NODES+1
    unsigned int* ebuf = (unsigned int*)(offs + N_NODES + 2); // 1.6M
    int* csr_src    = (int*)(ebuf + N_EDGES);              // 1.6M

    const int* src = ei;
    const int* dst = ei + N_EDGES;

    prep_kernel<<<PREP_X_BLOCKS + PREP_W1_BLOCKS + PREP_W2_BLOCKS, 256, 0, stream>>>(
        x, W1, W2, xb, W1T, W2T);
    ghist_kernel<<<BIN_BLOCKS, 256, 0, stream>>>(dst, histT);
    scanA_kernel<<<NBK, 256, 0, stream>>>(histT, blockBaseP, bktTotal);
    scanB_kernel<<<1, 1024, 0, stream>>>(bktTotal, bktBase);
    bin_kernel<<<BIN_BLOCKS, 256, 0, stream>>>(src, dst, blockBaseP, bktBase, ebuf);
    group_kernel<<<NBK, 256, 0, stream>>>(ebuf, bktBase, bktTotal, csr_src, offs);
    gather_kernel<<<N_NODES / 8, 256, 0, stream>>>(xb, eps, offs, csr_src, h_in);

    gemm1_mfma<<<(N_NODES + 63) / 64, 256, 0, stream>>>(h_in, W1T, b1, h1);
    gemm2_mfma<<<(N_NODES + 63) / 64, 256, 0, stream>>>(h1, W2T, b2, out);
}

// Round 6
// 251.995 us; speedup vs baseline: 6.0974x; 1.1674x over previous
//
#include <hip/hip_runtime.h>

#define N_NODES 100000
#define IN_CH 128
#define HID_CH 256
#define OUT_CH 128
#define N_EDGES 1600000

#define NBK 782                                   // ceil(N_NODES/128) buckets of 128 nodes
#define BIN_BLOCKS 256
#define EPB (N_EDGES / BIN_BLOCKS)                // 6250 edges per bin block

typedef __attribute__((ext_vector_type(8))) short short8;
typedef __attribute__((ext_vector_type(4))) float f32x4;

// bf16 <-> f32 helpers (bit ops; finite data only)
__device__ __forceinline__ float b2f(ushort u) {
    unsigned int x = ((unsigned int)u) << 16;
    return __uint_as_float(x);
}
__device__ __forceinline__ ushort f2b(float f) {
    unsigned int u = __float_as_uint(f);
    u += 0x7FFFu + ((u >> 16) & 1u);   // round-to-nearest-even
    return (ushort)(u >> 16);
}

// ---------------------------------------------------------------------------
// Prep: x fp32 -> xb bf16 ; W1 [128][256] -> W1T bf16 [256][128] ;
//       W2 [256][128] -> W2T bf16 [128][256]
// ---------------------------------------------------------------------------
#define PREP_X_BLOCKS 6250
#define PREP_W1_BLOCKS 128
#define PREP_W2_BLOCKS 128
__global__ __launch_bounds__(256) void prep_kernel(
    const float* __restrict__ x, const float* __restrict__ W1,
    const float* __restrict__ W2,
    ushort* __restrict__ xb, ushort* __restrict__ W1T,
    ushort* __restrict__ W2T) {
    const int b = blockIdx.x;
    const int t = threadIdx.x;
    if (b < PREP_X_BLOCKS) {
        const size_t i = (size_t)b * 2048 + t * 8;
        float4 a = *reinterpret_cast<const float4*>(x + i);
        float4 c = *reinterpret_cast<const float4*>(x + i + 4);
        ushort v[8] = {f2b(a.x), f2b(a.y), f2b(a.z), f2b(a.w),
                       f2b(c.x), f2b(c.y), f2b(c.z), f2b(c.w)};
        *reinterpret_cast<short8*>(xb + i) = *reinterpret_cast<short8*>(v);
    } else if (b < PREP_X_BLOCKS + PREP_W1_BLOCKS) {
        const int i = (b - PREP_X_BLOCKS) * 256 + t;     // oc*128 + k
        const int oc = i >> 7, k = i & 127;
        W1T[i] = f2b(W1[k * HID_CH + oc]);
    } else {
        const int i = (b - PREP_X_BLOCKS - PREP_W1_BLOCKS) * 256 + t; // oc*256+k
        const int oc = i >> 8, k = i & 255;
        W2T[i] = f2b(W2[k * OUT_CH + oc]);
    }
}

// ---------------------------------------------------------------------------
// Bucketing step 1: per-(block,bucket) histogram (LDS), transposed store.
// ---------------------------------------------------------------------------
__global__ __launch_bounds__(256) void ghist_kernel(
    const int* __restrict__ dst, int* __restrict__ histT) {
    __shared__ int h[NBK];
    const int b = blockIdx.x, t = threadIdx.x;
    for (int k = t; k < NBK; k += 256) h[k] = 0;
    __syncthreads();
    const int base = b * EPB;
    for (int i = t; i < EPB; i += 256)
        atomicAdd(&h[dst[base + i] >> 7], 1);
    __syncthreads();
    for (int k = t; k < NBK; k += 256) histT[k * BIN_BLOCKS + b] = h[k];
}

// ---------------------------------------------------------------------------
// Bucketing step 2a: per-bucket exclusive scan over the 256 block counts.
// ---------------------------------------------------------------------------
__global__ __launch_bounds__(256) void scanA_kernel(
    const int* __restrict__ histT, int* __restrict__ blockBaseP,
    int* __restrict__ bktTotal) {
    __shared__ int ts[256];
    const int bk = blockIdx.x, t = threadIdx.x;
    const int v = histT[bk * BIN_BLOCKS + t];
    ts[t] = v;
    __syncthreads();
    #pragma unroll
    for (int o = 1; o < 256; o <<= 1) {
        int add = (t >= o) ? ts[t - o] : 0;
        __syncthreads();
        ts[t] += add;
        __syncthreads();
    }
    blockBaseP[bk * BIN_BLOCKS + t] = ts[t] - v;
    if (t == 255) bktTotal[bk] = ts[255];
}

// ---------------------------------------------------------------------------
// Bucketing step 2b: exclusive scan of the 782 bucket totals (1 block).
// ---------------------------------------------------------------------------
__global__ __launch_bounds__(1024) void scanB_kernel(
    const int* __restrict__ bktTotal, int* __restrict__ bktBase) {
    __shared__ int ts[1024];
    const int t = threadIdx.x;
    const int v = (t < NBK) ? bktTotal[t] : 0;
    ts[t] = v;
    __syncthreads();
    #pragma unroll
    for (int o = 1; o < 1024; o <<= 1) {
        int add = (t >= o) ? ts[t - o] : 0;
        __syncthreads();
        ts[t] += add;
        __syncthreads();
    }
    if (t < NBK) bktBase[t] = ts[t] - v;
}

// ---------------------------------------------------------------------------
// Bucketing step 3: scatter packed entries (dl<<17 | src) into per-block
// contiguous runs inside each bucket region. LDS cursors only.
// ---------------------------------------------------------------------------
__global__ __launch_bounds__(256) void bin_kernel(
    const int* __restrict__ src, const int* __restrict__ dst,
    const int* __restrict__ blockBaseP, const int* __restrict__ bktBase,
    unsigned int* __restrict__ ebuf) {
    __shared__ int base[NBK];
    __shared__ int cur[NBK];
    const int b = blockIdx.x, t = threadIdx.x;
    for (int k = t; k < NBK; k += 256) {
        base[k] = bktBase[k] + blockBaseP[k * BIN_BLOCKS + b];
        cur[k] = 0;
    }
    __syncthreads();
    const int ebase = b * EPB;
    for (int i = t; i < EPB; i += 256) {
        const int d = dst[ebase + i];
        const int s = src[ebase + i];
        const int bk = d >> 7;
        const int r = atomicAdd(&cur[bk], 1);
        ebuf[base[bk] + r] = ((unsigned int)(d & 127) << 17) | (unsigned int)s;
    }
}

// ---------------------------------------------------------------------------
// Bucketing step 4: node-sort each bucket -> exact CSR.
// ---------------------------------------------------------------------------
__global__ __launch_bounds__(256) void group_kernel(
    const unsigned int* __restrict__ ebuf,
    const int* __restrict__ bktBase, const int* __restrict__ bktTotal,
    int* __restrict__ csr_src, int* __restrict__ offs) {
    __shared__ int hist[128];
    __shared__ int cur[128];
    const int bk = blockIdx.x, t = threadIdx.x;
    if (t < 128) hist[t] = 0;
    __syncthreads();
    const int start = bktBase[bk];
    const int cnt   = bktTotal[bk];
    for (int i = t; i < cnt; i += 256)
        atomicAdd(&hist[ebuf[start + i] >> 17], 1);
    __syncthreads();
    int v = (t < 128) ? hist[t] : 0;
    #pragma unroll
    for (int o = 1; o < 128; o <<= 1) {
        int add = (t < 128 && t >= o) ? hist[t - o] : 0;
        __syncthreads();
        if (t < 128) hist[t] += add;
        __syncthreads();
    }
    if (t < 128) {
        const int excl = hist[t] - v;
        cur[t] = excl;
        const int node = bk * 128 + t;
        if (node < N_NODES) offs[node] = start + excl;
    }
    if (bk == 0 && t == 0) offs[N_NODES] = N_EDGES;
    __syncthreads();
    for (int i = t; i < cnt; i += 256) {
        const unsigned int e = ebuf[start + i];
        const int dl = e >> 17;
        const int p = atomicAdd(&cur[dl], 1);
        csr_src[start + p] = (int)(e & 0x1FFFF);
    }
}

// ---------------------------------------------------------------------------
// Gather-aggregate fused with GIN self-term (bf16 rows, fp32 accum):
//   h_in[i] = bf16( (1+eps)*x[i] + sum_{j in N(i)} x[j] )
// 8 nodes/block, 32 threads/node. MLP version: per 32-edge tile, each lane
// loads one CSR index (coalesced), then 4 independent accumulator chains
// consume the tile via shfl-broadcast -> >=4 row loads in flight per group.
// ---------------------------------------------------------------------------
__global__ __launch_bounds__(256) void gather_kernel(
    const ushort* __restrict__ xb,
    const float* __restrict__ eps_p,
    const int* __restrict__ offs,
    const int* __restrict__ csr_src,
    ushort* __restrict__ h_in) {
    const int node = blockIdx.x * 8 + (threadIdx.x >> 5);
    const int l32 = threadIdx.x & 31;
    const int c = l32 * 4;
    const int beg = offs[node];
    const int end = offs[node + 1];

    float4 A0 = {0.f,0.f,0.f,0.f}, A1 = {0.f,0.f,0.f,0.f};
    float4 A2 = {0.f,0.f,0.f,0.f}, A3 = {0.f,0.f,0.f,0.f};

    for (int base = beg; base < end; base += 32) {
        const int nn = min(32, end - base);
        const int sidx = csr_src[base + min(l32, nn - 1)];
        int i = 0;
        for (; i + 4 <= nn; i += 4) {
            const int s0 = __shfl(sidx, i + 0, 32);
            const int s1 = __shfl(sidx, i + 1, 32);
            const int s2 = __shfl(sidx, i + 2, 32);
            const int s3 = __shfl(sidx, i + 3, 32);
            ushort4 v0 = *reinterpret_cast<const ushort4*>(xb + (size_t)s0 * IN_CH + c);
            ushort4 v1 = *reinterpret_cast<const ushort4*>(xb + (size_t)s1 * IN_CH + c);
            ushort4 v2 = *reinterpret_cast<const ushort4*>(xb + (size_t)s2 * IN_CH + c);
            ushort4 v3 = *reinterpret_cast<const ushort4*>(xb + (size_t)s3 * IN_CH + c);
            A0.x += b2f(v0.x); A0.y += b2f(v0.y); A0.z += b2f(v0.z); A0.w += b2f(v0.w);
            A1.x += b2f(v1.x); A1.y += b2f(v1.y); A1.z += b2f(v1.z); A1.w += b2f(v1.w);
            A2.x += b2f(v2.x); A2.y += b2f(v2.y); A2.z += b2f(v2.z); A2.w += b2f(v2.w);
            A3.x += b2f(v3.x); A3.y += b2f(v3.y); A3.z += b2f(v3.z); A3.w += b2f(v3.w);
        }
        for (; i < nn; ++i) {
            const int s = __shfl(sidx, i, 32);
            ushort4 v = *reinterpret_cast<const ushort4*>(xb + (size_t)s * IN_CH + c);
            A0.x += b2f(v.x); A0.y += b2f(v.y); A0.z += b2f(v.z); A0.w += b2f(v.w);
        }
    }

    const float a0 = A0.x + A1.x + A2.x + A3.x;
    const float a1 = A0.y + A1.y + A2.y + A3.y;
    const float a2 = A0.z + A1.z + A2.z + A3.z;
    const float a3 = A0.w + A1.w + A2.w + A3.w;

    const float scale = 1.0f + eps_p[0];
    ushort4 sv = *reinterpret_cast<const ushort4*>(xb + (size_t)node * IN_CH + c);
    ushort4 o;
    o.x = f2b(scale * b2f(sv.x) + a0);
    o.y = f2b(scale * b2f(sv.y) + a1);
    o.z = f2b(scale * b2f(sv.z) + a2);
    o.w = f2b(scale * b2f(sv.w) + a3);
    *reinterpret_cast<ushort4*>(h_in + (size_t)node * IN_CH + c) = o;
}

// ---------------------------------------------------------------------------
// GEMM1 (MFMA): h1 = bf16(relu(h_in @ W1 + b1))   [N,128]@[128,256] -> [N,256]
// ---------------------------------------------------------------------------
__global__ __launch_bounds__(256) void gemm1_mfma(
    const ushort* __restrict__ h_in,
    const ushort* __restrict__ W1T,
    const float* __restrict__ b1,
    ushort* __restrict__ h1) {
    const int w    = threadIdx.x >> 6;
    const int lane = threadIdx.x & 63;
    const int lr   = lane & 15;
    const int lk   = lane >> 4;
    const int arow = blockIdx.x * 64 + w * 16 + lr;
    const int arc  = arow < N_NODES ? arow : N_NODES - 1;

    short8 a[4];
    const ushort* ap = h_in + (size_t)arc * IN_CH + lk * 8;
    #pragma unroll
    for (int kk = 0; kk < 4; ++kk)
        a[kk] = *reinterpret_cast<const short8*>(ap + kk * 32);

    f32x4 acc[16];
    #pragma unroll
    for (int ct = 0; ct < 16; ++ct) acc[ct] = (f32x4){0.f, 0.f, 0.f, 0.f};

    #pragma unroll
    for (int ct = 0; ct < 16; ++ct) {
        const ushort* bp = W1T + (size_t)(ct * 16 + lr) * IN_CH + lk * 8;
        #pragma unroll
        for (int kk = 0; kk < 4; ++kk) {
            short8 b = *reinterpret_cast<const short8*>(bp + kk * 32);
            acc[ct] = __builtin_amdgcn_mfma_f32_16x16x32_bf16(a[kk], b, acc[ct], 0, 0, 0);
        }
    }

    const int orow0 = blockIdx.x * 64 + w * 16 + lk * 4;
    #pragma unroll
    for (int ct = 0; ct < 16; ++ct) {
        const int col = ct * 16 + lr;
        const float bb = b1[col];
        #pragma unroll
        for (int r = 0; r < 4; ++r) {
            const int orow = orow0 + r;
            if (orow < N_NODES) {
                float v = fmaxf(acc[ct][r] + bb, 0.0f);
                h1[(size_t)orow * HID_CH + col] = f2b(v);
            }
        }
    }
}

// ---------------------------------------------------------------------------
// GEMM2 (MFMA) + fused bias/relu/log_softmax -> fp32 out
// ---------------------------------------------------------------------------
__global__ __launch_bounds__(256) void gemm2_mfma(
    const ushort* __restrict__ h1,
    const ushort* __restrict__ W2T,
    const float* __restrict__ b2,
    float* __restrict__ out) {
    const int w    = threadIdx.x >> 6;
    const int lane = threadIdx.x & 63;
    const int lr   = lane & 15;
    const int lk   = lane >> 4;
    const int arow = blockIdx.x * 64 + w * 16 + lr;
    const int arc  = arow < N_NODES ? arow : N_NODES - 1;

    short8 a[8];
    const ushort* ap = h1 + (size_t)arc * HID_CH + lk * 8;
    #pragma unroll
    for (int kk = 0; kk < 8; ++kk)
        a[kk] = *reinterpret_cast<const short8*>(ap + kk * 32);

    f32x4 acc[8];
    #pragma unroll
    for (int ct = 0; ct < 8; ++ct) acc[ct] = (f32x4){0.f, 0.f, 0.f, 0.f};

    #pragma unroll
    for (int ct = 0; ct < 8; ++ct) {
        const ushort* bp = W2T + (size_t)(ct * 16 + lr) * HID_CH + lk * 8;
        #pragma unroll
        for (int kk = 0; kk < 8; ++kk) {
            short8 b = *reinterpret_cast<const short8*>(bp + kk * 32);
            acc[ct] = __builtin_amdgcn_mfma_f32_16x16x32_bf16(a[kk], b, acc[ct], 0, 0, 0);
        }
    }

    float bias[8];
    #pragma unroll
    for (int ct = 0; ct < 8; ++ct) bias[ct] = b2[ct * 16 + lr];

    const int orow0 = blockIdx.x * 64 + w * 16 + lk * 4;
    #pragma unroll
    for (int r = 0; r < 4; ++r) {
        float v[8];
        float m = -1e30f;
        #pragma unroll
        for (int ct = 0; ct < 8; ++ct) {
            v[ct] = fmaxf(acc[ct][r] + bias[ct], 0.0f);
            m = fmaxf(m, v[ct]);
        }
        #pragma unroll
        for (int o = 1; o < 16; o <<= 1) m = fmaxf(m, __shfl_xor(m, o));
        float s = 0.0f;
        #pragma unroll
        for (int ct = 0; ct < 8; ++ct) s += __expf(v[ct] - m);
        #pragma unroll
        for (int o = 1; o < 16; o <<= 1) s += __shfl_xor(s, o);
        const float lse = m + __logf(s);
        const int orow = orow0 + r;
        if (orow < N_NODES) {
            #pragma unroll
            for (int ct = 0; ct < 8; ++ct)
                out[(size_t)orow * OUT_CH + ct * 16 + lr] = v[ct] - lse;
        }
    }
}

extern "C" void kernel_launch(void* const* d_in, const int* in_sizes, int n_in,
                              void* d_out, int out_size, void* d_ws, size_t ws_size,
                              hipStream_t stream) {
    const float* x    = (const float*)d_in[0];
    const int*   ei   = (const int*)d_in[1];
    const float* W1   = (const float*)d_in[2];
    const float* b1   = (const float*)d_in[3];
    const float* W2   = (const float*)d_in[4];
    const float* b2   = (const float*)d_in[5];
    const float* eps  = (const float*)d_in[6];
    float* out = (float*)d_out;

    // workspace layout
    ushort* xb   = (ushort*)d_ws;                          // 12.8M ushort
    ushort* h_in = xb + (size_t)N_NODES * IN_CH;           // 12.8M
    ushort* h1   = h_in + (size_t)N_NODES * IN_CH;         // 25.6M
    ushort* W1T  = h1 + (size_t)N_NODES * HID_CH;          // 32768
    ushort* W2T  = W1T + IN_CH * HID_CH;                   // 32768
    int* histT      = (int*)(W2T + HID_CH * OUT_CH);       // NBK*256
    int* blockBaseP = histT + NBK * BIN_BLOCKS;            // NBK*256
    int* bktTotal   = blockBaseP + NBK * BIN_BLOCKS;       // NBK
    int* bktBase    = bktTotal + NBK;                      // NBK
    int* offs       = bktBase + NBK;                       // N_NODES+1
    unsigned int* ebuf = (unsigned int*)(offs + N_NODES + 2); // 1.6M
    int* csr_src    = (int*)(ebuf + N_EDGES);              // 1.6M

    const int* src = ei;
    const int* dst = ei + N_EDGES;

    prep_kernel<<<PREP_X_BLOCKS + PREP_W1_BLOCKS + PREP_W2_BLOCKS, 256, 0, stream>>>(
        x, W1, W2, xb, W1T, W2T);
    ghist_kernel<<<BIN_BLOCKS, 256, 0, stream>>>(dst, histT);
    scanA_kernel<<<NBK, 256, 0, stream>>>(histT, blockBaseP, bktTotal);
    scanB_kernel<<<1, 1024, 0, stream>>>(bktTotal, bktBase);
    bin_kernel<<<BIN_BLOCKS, 256, 0, stream>>>(src, dst, blockBaseP, bktBase, ebuf);
    group_kernel<<<NBK, 256, 0, stream>>>(ebuf, bktBase, bktTotal, csr_src, offs);
    gather_kernel<<<N_NODES / 8, 256, 0, stream>>>(xb, eps, offs, csr_src, h_in);

    gemm1_mfma<<<(N_NODES + 63) / 64, 256, 0, stream>>>(h_in, W1T, b1, h1);
    gemm2_mfma<<<(N_NODES + 63) / 64, 256, 0, stream>>>(h1, W2T, b2, out);
}

// Round 7
// 224.559 us; speedup vs baseline: 6.8424x; 1.1222x over previous
//
#include <hip/hip_runtime.h>

#define N_NODES 100000
#define IN_CH 128
#define HID_CH 256
#define OUT_CH 128
#define N_EDGES 1600000

#define NBK 782                                   // ceil(N_NODES/128) buckets of 128 nodes
#define BIN_BLOCKS 256
#define EPB (N_EDGES / BIN_BLOCKS)                // 6250 edges per bin block

typedef __attribute__((ext_vector_type(8))) short short8;
typedef __attribute__((ext_vector_type(4))) float f32x4;

// bf16 <-> f32 helpers (bit ops; finite data only)
__device__ __forceinline__ float b2f(ushort u) {
    unsigned int x = ((unsigned int)u) << 16;
    return __uint_as_float(x);
}
__device__ __forceinline__ ushort f2b(float f) {
    unsigned int u = __float_as_uint(f);
    u += 0x7FFFu + ((u >> 16) & 1u);   // round-to-nearest-even
    return (ushort)(u >> 16);
}

// ---------------------------------------------------------------------------
// Prep: x fp32 -> xb bf16 ; W1 [128][256] -> W1T bf16 [256][128] ;
//       W2 [256][128] -> W2T bf16 [128][256]
// ---------------------------------------------------------------------------
#define PREP_X_BLOCKS 6250
#define PREP_W1_BLOCKS 128
#define PREP_W2_BLOCKS 128
__global__ __launch_bounds__(256) void prep_kernel(
    const float* __restrict__ x, const float* __restrict__ W1,
    const float* __restrict__ W2,
    ushort* __restrict__ xb, ushort* __restrict__ W1T,
    ushort* __restrict__ W2T) {
    const int b = blockIdx.x;
    const int t = threadIdx.x;
    if (b < PREP_X_BLOCKS) {
        const size_t i = (size_t)b * 2048 + t * 8;
        float4 a = *reinterpret_cast<const float4*>(x + i);
        float4 c = *reinterpret_cast<const float4*>(x + i + 4);
        ushort v[8] = {f2b(a.x), f2b(a.y), f2b(a.z), f2b(a.w),
                       f2b(c.x), f2b(c.y), f2b(c.z), f2b(c.w)};
        *reinterpret_cast<short8*>(xb + i) = *reinterpret_cast<short8*>(v);
    } else if (b < PREP_X_BLOCKS + PREP_W1_BLOCKS) {
        const int i = (b - PREP_X_BLOCKS) * 256 + t;     // oc*128 + k
        const int oc = i >> 7, k = i & 127;
        W1T[i] = f2b(W1[k * HID_CH + oc]);
    } else {
        const int i = (b - PREP_X_BLOCKS - PREP_W1_BLOCKS) * 256 + t; // oc*256+k
        const int oc = i >> 8, k = i & 255;
        W2T[i] = f2b(W2[k * OUT_CH + oc]);
    }
}

// ---------------------------------------------------------------------------
// Bucketing step 1: per-(block,bucket) histogram (LDS), transposed store.
// ---------------------------------------------------------------------------
__global__ __launch_bounds__(256) void ghist_kernel(
    const int* __restrict__ dst, int* __restrict__ histT) {
    __shared__ int h[NBK];
    const int b = blockIdx.x, t = threadIdx.x;
    for (int k = t; k < NBK; k += 256) h[k] = 0;
    __syncthreads();
    const int base = b * EPB;
    for (int i = t; i < EPB; i += 256)
        atomicAdd(&h[dst[base + i] >> 7], 1);
    __syncthreads();
    for (int k = t; k < NBK; k += 256) histT[k * BIN_BLOCKS + b] = h[k];
}

// ---------------------------------------------------------------------------
// Bucketing step 2a: per-bucket exclusive scan over the 256 block counts.
// ---------------------------------------------------------------------------
__global__ __launch_bounds__(256) void scanA_kernel(
    const int* __restrict__ histT, int* __restrict__ blockBaseP,
    int* __restrict__ bktTotal) {
    __shared__ int ts[256];
    const int bk = blockIdx.x, t = threadIdx.x;
    const int v = histT[bk * BIN_BLOCKS + t];
    ts[t] = v;
    __syncthreads();
    #pragma unroll
    for (int o = 1; o < 256; o <<= 1) {
        int add = (t >= o) ? ts[t - o] : 0;
        __syncthreads();
        ts[t] += add;
        __syncthreads();
    }
    blockBaseP[bk * BIN_BLOCKS + t] = ts[t] - v;
    if (t == 255) bktTotal[bk] = ts[255];
}

// ---------------------------------------------------------------------------
// Bucketing step 2b: exclusive scan of the 782 bucket totals (1 block).
// ---------------------------------------------------------------------------
__global__ __launch_bounds__(1024) void scanB_kernel(
    const int* __restrict__ bktTotal, int* __restrict__ bktBase) {
    __shared__ int ts[1024];
    const int t = threadIdx.x;
    const int v = (t < NBK) ? bktTotal[t] : 0;
    ts[t] = v;
    __syncthreads();
    #pragma unroll
    for (int o = 1; o < 1024; o <<= 1) {
        int add = (t >= o) ? ts[t - o] : 0;
        __syncthreads();
        ts[t] += add;
        __syncthreads();
    }
    if (t < NBK) bktBase[t] = ts[t] - v;
}

// ---------------------------------------------------------------------------
// Bucketing step 3: scatter packed entries (dl<<17 | src) into per-block
// contiguous runs inside each bucket region. LDS cursors only.
// ---------------------------------------------------------------------------
__global__ __launch_bounds__(256) void bin_kernel(
    const int* __restrict__ src, const int* __restrict__ dst,
    const int* __restrict__ blockBaseP, const int* __restrict__ bktBase,
    unsigned int* __restrict__ ebuf) {
    __shared__ int base[NBK];
    __shared__ int cur[NBK];
    const int b = blockIdx.x, t = threadIdx.x;
    for (int k = t; k < NBK; k += 256) {
        base[k] = bktBase[k] + blockBaseP[k * BIN_BLOCKS + b];
        cur[k] = 0;
    }
    __syncthreads();
    const int ebase = b * EPB;
    for (int i = t; i < EPB; i += 256) {
        const int d = dst[ebase + i];
        const int s = src[ebase + i];
        const int bk = d >> 7;
        const int r = atomicAdd(&cur[bk], 1);
        ebuf[base[bk] + r] = ((unsigned int)(d & 127) << 17) | (unsigned int)s;
    }
}

// ---------------------------------------------------------------------------
// Bucketing step 4: node-sort each bucket -> exact CSR.
// ---------------------------------------------------------------------------
__global__ __launch_bounds__(256) void group_kernel(
    const unsigned int* __restrict__ ebuf,
    const int* __restrict__ bktBase, const int* __restrict__ bktTotal,
    int* __restrict__ csr_src, int* __restrict__ offs) {
    __shared__ int hist[128];
    __shared__ int cur[128];
    const int bk = blockIdx.x, t = threadIdx.x;
    if (t < 128) hist[t] = 0;
    __syncthreads();
    const int start = bktBase[bk];
    const int cnt   = bktTotal[bk];
    for (int i = t; i < cnt; i += 256)
        atomicAdd(&hist[ebuf[start + i] >> 17], 1);
    __syncthreads();
    int v = (t < 128) ? hist[t] : 0;
    #pragma unroll
    for (int o = 1; o < 128; o <<= 1) {
        int add = (t < 128 && t >= o) ? hist[t - o] : 0;
        __syncthreads();
        if (t < 128) hist[t] += add;
        __syncthreads();
    }
    if (t < 128) {
        const int excl = hist[t] - v;
        cur[t] = excl;
        const int node = bk * 128 + t;
        if (node < N_NODES) offs[node] = start + excl;
    }
    if (bk == 0 && t == 0) offs[N_NODES] = N_EDGES;
    __syncthreads();
    for (int i = t; i < cnt; i += 256) {
        const unsigned int e = ebuf[start + i];
        const int dl = e >> 17;
        const int p = atomicAdd(&cur[dl], 1);
        csr_src[start + p] = (int)(e & 0x1FFFF);
    }
}

// ---------------------------------------------------------------------------
// Gather-aggregate fused with GIN self-term (bf16 rows, fp32 accum):
//   h_in[i] = bf16( (1+eps)*x[i] + sum_{j in N(i)} x[j] )
// 8 nodes/block, 32 threads/node; 32-edge tiles, 4 independent acc chains.
// ---------------------------------------------------------------------------
__global__ __launch_bounds__(256) void gather_kernel(
    const ushort* __restrict__ xb,
    const float* __restrict__ eps_p,
    const int* __restrict__ offs,
    const int* __restrict__ csr_src,
    ushort* __restrict__ h_in) {
    const int node = blockIdx.x * 8 + (threadIdx.x >> 5);
    const int l32 = threadIdx.x & 31;
    const int c = l32 * 4;
    const int beg = offs[node];
    const int end = offs[node + 1];

    float4 A0 = {0.f,0.f,0.f,0.f}, A1 = {0.f,0.f,0.f,0.f};
    float4 A2 = {0.f,0.f,0.f,0.f}, A3 = {0.f,0.f,0.f,0.f};

    for (int base = beg; base < end; base += 32) {
        const int nn = min(32, end - base);
        const int sidx = csr_src[base + min(l32, nn - 1)];
        int i = 0;
        for (; i + 4 <= nn; i += 4) {
            const int s0 = __shfl(sidx, i + 0, 32);
            const int s1 = __shfl(sidx, i + 1, 32);
            const int s2 = __shfl(sidx, i + 2, 32);
            const int s3 = __shfl(sidx, i + 3, 32);
            ushort4 v0 = *reinterpret_cast<const ushort4*>(xb + (size_t)s0 * IN_CH + c);
            ushort4 v1 = *reinterpret_cast<const ushort4*>(xb + (size_t)s1 * IN_CH + c);
            ushort4 v2 = *reinterpret_cast<const ushort4*>(xb + (size_t)s2 * IN_CH + c);
            ushort4 v3 = *reinterpret_cast<const ushort4*>(xb + (size_t)s3 * IN_CH + c);
            A0.x += b2f(v0.x); A0.y += b2f(v0.y); A0.z += b2f(v0.z); A0.w += b2f(v0.w);
            A1.x += b2f(v1.x); A1.y += b2f(v1.y); A1.z += b2f(v1.z); A1.w += b2f(v1.w);
            A2.x += b2f(v2.x); A2.y += b2f(v2.y); A2.z += b2f(v2.z); A2.w += b2f(v2.w);
            A3.x += b2f(v3.x); A3.y += b2f(v3.y); A3.z += b2f(v3.z); A3.w += b2f(v3.w);
        }
        for (; i < nn; ++i) {
            const int s = __shfl(sidx, i, 32);
            ushort4 v = *reinterpret_cast<const ushort4*>(xb + (size_t)s * IN_CH + c);
            A0.x += b2f(v.x); A0.y += b2f(v.y); A0.z += b2f(v.z); A0.w += b2f(v.w);
        }
    }

    const float a0 = A0.x + A1.x + A2.x + A3.x;
    const float a1 = A0.y + A1.y + A2.y + A3.y;
    const float a2 = A0.z + A1.z + A2.z + A3.z;
    const float a3 = A0.w + A1.w + A2.w + A3.w;

    const float scale = 1.0f + eps_p[0];
    ushort4 sv = *reinterpret_cast<const ushort4*>(xb + (size_t)node * IN_CH + c);
    ushort4 o;
    o.x = f2b(scale * b2f(sv.x) + a0);
    o.y = f2b(scale * b2f(sv.y) + a1);
    o.z = f2b(scale * b2f(sv.z) + a2);
    o.w = f2b(scale * b2f(sv.w) + a3);
    *reinterpret_cast<ushort4*>(h_in + (size_t)node * IN_CH + c) = o;
}

// ---------------------------------------------------------------------------
// Fused MLP (MFMA): out = log_softmax(relu(relu(h_in@W1+b1)@W2+b2))
// Barrier-free: each wave owns 16 rows end-to-end. h1 tile (16x256 bf16)
// parked in a private LDS region with row stride 264 halves (528 B) so the
// phase-2 ds_read_b128 is only a free 2-way bank alias.
// Block = 256 thr = 4 waves = 64 rows. Grid = ceil(N/64).
// ---------------------------------------------------------------------------
#define H1_LD 264          // padded row stride in halves
__global__ __launch_bounds__(256) void mlp_fused(
    const ushort* __restrict__ h_in,
    const ushort* __restrict__ W1T,
    const ushort* __restrict__ W2T,
    const float* __restrict__ b1,
    const float* __restrict__ b2,
    float* __restrict__ out) {
    __shared__ ushort h1s[4][16 * H1_LD];    // 33792 B
    const int w    = threadIdx.x >> 6;
    const int lane = threadIdx.x & 63;
    const int lr   = lane & 15;
    const int lk   = lane >> 4;
    const int row0 = blockIdx.x * 64 + w * 16;
    const int arow = row0 + lr;
    const int arc  = arow < N_NODES ? arow : N_NODES - 1;
    ushort* tile = h1s[w];

    // ---- phase 1: h1 = relu(h_in @ W1 + b1), 16 rows x 256 cols ----
    short8 a[4];
    const ushort* ap = h_in + (size_t)arc * IN_CH + lk * 8;
    #pragma unroll
    for (int kk = 0; kk < 4; ++kk)
        a[kk] = *reinterpret_cast<const short8*>(ap + kk * 32);

    #pragma unroll
    for (int ct = 0; ct < 16; ++ct) {
        f32x4 acc = (f32x4){0.f, 0.f, 0.f, 0.f};
        const ushort* bp = W1T + (size_t)(ct * 16 + lr) * IN_CH + lk * 8;
        #pragma unroll
        for (int kk = 0; kk < 4; ++kk) {
            short8 b = *reinterpret_cast<const short8*>(bp + kk * 32);
            acc = __builtin_amdgcn_mfma_f32_16x16x32_bf16(a[kk], b, acc, 0, 0, 0);
        }
        // epilogue 1 -> LDS: value (row = lk*4+r, col = ct*16+lr)
        const float bb = b1[ct * 16 + lr];
        #pragma unroll
        for (int r = 0; r < 4; ++r) {
            float v = fmaxf(acc[r] + bb, 0.0f);
            tile[(lk * 4 + r) * H1_LD + ct * 16 + lr] = f2b(v);
        }
    }

    // ---- phase 2: out = lsm(relu(h1 @ W2 + b2)), 16 rows x 128 cols ----
    // A-frags from LDS: row = lr, k = lk*8 + kk*32  (compiler inserts lgkmcnt)
    short8 a2[8];
    #pragma unroll
    for (int kk = 0; kk < 8; ++kk)
        a2[kk] = *reinterpret_cast<const short8*>(tile + lr * H1_LD + lk * 8 + kk * 32);

    f32x4 acc2[8];
    #pragma unroll
    for (int ct = 0; ct < 8; ++ct) acc2[ct] = (f32x4){0.f, 0.f, 0.f, 0.f};

    #pragma unroll
    for (int ct = 0; ct < 8; ++ct) {
        const ushort* bp = W2T + (size_t)(ct * 16 + lr) * HID_CH + lk * 8;
        #pragma unroll
        for (int kk = 0; kk < 8; ++kk) {
            short8 b = *reinterpret_cast<const short8*>(bp + kk * 32);
            acc2[ct] = __builtin_amdgcn_mfma_f32_16x16x32_bf16(a2[kk], b, acc2[ct], 0, 0, 0);
        }
    }

    float bias[8];
    #pragma unroll
    for (int ct = 0; ct < 8; ++ct) bias[ct] = b2[ct * 16 + lr];

    const int orow0 = row0 + lk * 4;
    #pragma unroll
    for (int r = 0; r < 4; ++r) {
        float v[8];
        float m = -1e30f;
        #pragma unroll
        for (int ct = 0; ct < 8; ++ct) {
            v[ct] = fmaxf(acc2[ct][r] + bias[ct], 0.0f);
            m = fmaxf(m, v[ct]);
        }
        #pragma unroll
        for (int o = 1; o < 16; o <<= 1) m = fmaxf(m, __shfl_xor(m, o));
        float s = 0.0f;
        #pragma unroll
        for (int ct = 0; ct < 8; ++ct) s += __expf(v[ct] - m);
        #pragma unroll
        for (int o = 1; o < 16; o <<= 1) s += __shfl_xor(s, o);
        const float lse = m + __logf(s);
        const int orow = orow0 + r;
        if (orow < N_NODES) {
            #pragma unroll
            for (int ct = 0; ct < 8; ++ct)
                out[(size_t)orow * OUT_CH + ct * 16 + lr] = v[ct] - lse;
        }
    }
}

extern "C" void kernel_launch(void* const* d_in, const int* in_sizes, int n_in,
                              void* d_out, int out_size, void* d_ws, size_t ws_size,
                              hipStream_t stream) {
    const float* x    = (const float*)d_in[0];
    const int*   ei   = (const int*)d_in[1];
    const float* W1   = (const float*)d_in[2];
    const float* b1   = (const float*)d_in[3];
    const float* W2   = (const float*)d_in[4];
    const float* b2   = (const float*)d_in[5];
    const float* eps  = (const float*)d_in[6];
    float* out = (float*)d_out;

    // workspace layout
    ushort* xb   = (ushort*)d_ws;                          // 12.8M ushort
    ushort* h_in = xb + (size_t)N_NODES * IN_CH;           // 12.8M
    ushort* W1T  = h_in + (size_t)N_NODES * IN_CH;         // 32768
    ushort* W2T  = W1T + IN_CH * HID_CH;                   // 32768
    int* histT      = (int*)(W2T + HID_CH * OUT_CH);       // NBK*256
    int* blockBaseP = histT + NBK * BIN_BLOCKS;            // NBK*256
    int* bktTotal   = blockBaseP + NBK * BIN_BLOCKS;       // NBK
    int* bktBase    = bktTotal + NBK;                      // NBK
    int* offs       = bktBase + NBK;                       // N_NODES+1
    unsigned int* ebuf = (unsigned int*)(offs + N_NODES + 2); // 1.6M
    int* csr_src    = (int*)(ebuf + N_EDGES);              // 1.6M

    const int* src = ei;
    const int* dst = ei + N_EDGES;

    prep_kernel<<<PREP_X_BLOCKS + PREP_W1_BLOCKS + PREP_W2_BLOCKS, 256, 0, stream>>>(
        x, W1, W2, xb, W1T, W2T);
    ghist_kernel<<<BIN_BLOCKS, 256, 0, stream>>>(dst, histT);
    scanA_kernel<<<NBK, 256, 0, stream>>>(histT, blockBaseP, bktTotal);
    scanB_kernel<<<1, 1024, 0, stream>>>(bktTotal, bktBase);
    bin_kernel<<<BIN_BLOCKS, 256, 0, stream>>>(src, dst, blockBaseP, bktBase, ebuf);
    group_kernel<<<NBK, 256, 0, stream>>>(ebuf, bktBase, bktTotal, csr_src, offs);
    gather_kernel<<<N_NODES / 8, 256, 0, stream>>>(xb, eps, offs, csr_src, h_in);

    mlp_fused<<<(N_NODES + 63) / 64, 256, 0, stream>>>(h_in, W1T, W2T, b1, b2, out);
}

// Round 8
// 166.102 us; speedup vs baseline: 9.2505x; 1.3519x over previous
//
#include <hip/hip_runtime.h>

#define N_NODES 100000
#define IN_CH 128
#define HID_CH 256
#define OUT_CH 128
#define N_EDGES 1600000

#define NBK 782                                   // ceil(N_NODES/128) buckets of 128 nodes
#define BIN_BLOCKS 256
#define EPB (N_EDGES / BIN_BLOCKS)                // 6250 edges per bin block

typedef __attribute__((ext_vector_type(8))) short short8;
typedef __attribute__((ext_vector_type(4))) float f32x4;

// bf16 <-> f32 helpers (bit ops; finite data only)
__device__ __forceinline__ float b2f(ushort u) {
    unsigned int x = ((unsigned int)u) << 16;
    return __uint_as_float(x);
}
__device__ __forceinline__ ushort f2b(float f) {
    unsigned int u = __float_as_uint(f);
    u += 0x7FFFu + ((u >> 16) & 1u);   // round-to-nearest-even
    return (ushort)(u >> 16);
}

// ---------------------------------------------------------------------------
// Prep: x fp32 -> xb bf16 ; W1 [128][256] -> W1T bf16 [256][128] ;
//       W2 [256][128] -> W2T bf16 [128][256]
// ---------------------------------------------------------------------------
#define PREP_X_BLOCKS 6250
#define PREP_W1_BLOCKS 128
#define PREP_W2_BLOCKS 128
__global__ __launch_bounds__(256) void prep_kernel(
    const float* __restrict__ x, const float* __restrict__ W1,
    const float* __restrict__ W2,
    ushort* __restrict__ xb, ushort* __restrict__ W1T,
    ushort* __restrict__ W2T) {
    const int b = blockIdx.x;
    const int t = threadIdx.x;
    if (b < PREP_X_BLOCKS) {
        const size_t i = (size_t)b * 2048 + t * 8;
        float4 a = *reinterpret_cast<const float4*>(x + i);
        float4 c = *reinterpret_cast<const float4*>(x + i + 4);
        ushort v[8] = {f2b(a.x), f2b(a.y), f2b(a.z), f2b(a.w),
                       f2b(c.x), f2b(c.y), f2b(c.z), f2b(c.w)};
        *reinterpret_cast<short8*>(xb + i) = *reinterpret_cast<short8*>(v);
    } else if (b < PREP_X_BLOCKS + PREP_W1_BLOCKS) {
        const int i = (b - PREP_X_BLOCKS) * 256 + t;     // oc*128 + k
        const int oc = i >> 7, k = i & 127;
        W1T[i] = f2b(W1[k * HID_CH + oc]);
    } else {
        const int i = (b - PREP_X_BLOCKS - PREP_W1_BLOCKS) * 256 + t; // oc*256+k
        const int oc = i >> 8, k = i & 255;
        W2T[i] = f2b(W2[k * OUT_CH + oc]);
    }
}

// ---------------------------------------------------------------------------
// Bucketing step 1: per-(block,bucket) histogram (LDS), transposed store.
// ---------------------------------------------------------------------------
__global__ __launch_bounds__(256) void ghist_kernel(
    const int* __restrict__ dst, int* __restrict__ histT) {
    __shared__ int h[NBK];
    const int b = blockIdx.x, t = threadIdx.x;
    for (int k = t; k < NBK; k += 256) h[k] = 0;
    __syncthreads();
    const int base = b * EPB;
    for (int i = t; i < EPB; i += 256)
        atomicAdd(&h[dst[base + i] >> 7], 1);
    __syncthreads();
    for (int k = t; k < NBK; k += 256) histT[k * BIN_BLOCKS + b] = h[k];
}

// ---------------------------------------------------------------------------
// Bucketing step 2a: per-bucket exclusive scan over the 256 block counts.
// ---------------------------------------------------------------------------
__global__ __launch_bounds__(256) void scanA_kernel(
    const int* __restrict__ histT, int* __restrict__ blockBaseP,
    int* __restrict__ bktTotal) {
    __shared__ int ts[256];
    const int bk = blockIdx.x, t = threadIdx.x;
    const int v = histT[bk * BIN_BLOCKS + t];
    ts[t] = v;
    __syncthreads();
    #pragma unroll
    for (int o = 1; o < 256; o <<= 1) {
        int add = (t >= o) ? ts[t - o] : 0;
        __syncthreads();
        ts[t] += add;
        __syncthreads();
    }
    blockBaseP[bk * BIN_BLOCKS + t] = ts[t] - v;
    if (t == 255) bktTotal[bk] = ts[255];
}

// ---------------------------------------------------------------------------
// Bucketing step 2b: exclusive scan of the 782 bucket totals (1 block).
// ---------------------------------------------------------------------------
__global__ __launch_bounds__(1024) void scanB_kernel(
    const int* __restrict__ bktTotal, int* __restrict__ bktBase) {
    __shared__ int ts[1024];
    const int t = threadIdx.x;
    const int v = (t < NBK) ? bktTotal[t] : 0;
    ts[t] = v;
    __syncthreads();
    #pragma unroll
    for (int o = 1; o < 1024; o <<= 1) {
        int add = (t >= o) ? ts[t - o] : 0;
        __syncthreads();
        ts[t] += add;
        __syncthreads();
    }
    if (t < NBK) bktBase[t] = ts[t] - v;
}

// ---------------------------------------------------------------------------
// Bucketing step 3: scatter packed entries (dl<<17 | src) into per-block
// contiguous runs inside each bucket region. LDS cursors only.
// ---------------------------------------------------------------------------
__global__ __launch_bounds__(256) void bin_kernel(
    const int* __restrict__ src, const int* __restrict__ dst,
    const int* __restrict__ blockBaseP, const int* __restrict__ bktBase,
    unsigned int* __restrict__ ebuf) {
    __shared__ int base[NBK];
    __shared__ int cur[NBK];
    const int b = blockIdx.x, t = threadIdx.x;
    for (int k = t; k < NBK; k += 256) {
        base[k] = bktBase[k] + blockBaseP[k * BIN_BLOCKS + b];
        cur[k] = 0;
    }
    __syncthreads();
    const int ebase = b * EPB;
    for (int i = t; i < EPB; i += 256) {
        const int d = dst[ebase + i];
        const int s = src[ebase + i];
        const int bk = d >> 7;
        const int r = atomicAdd(&cur[bk], 1);
        ebuf[base[bk] + r] = ((unsigned int)(d & 127) << 17) | (unsigned int)s;
    }
}

// ---------------------------------------------------------------------------
// Bucketing step 4: node-sort each bucket -> exact CSR.
// ---------------------------------------------------------------------------
__global__ __launch_bounds__(256) void group_kernel(
    const unsigned int* __restrict__ ebuf,
    const int* __restrict__ bktBase, const int* __restrict__ bktTotal,
    int* __restrict__ csr_src, int* __restrict__ offs) {
    __shared__ int hist[128];
    __shared__ int cur[128];
    const int bk = blockIdx.x, t = threadIdx.x;
    if (t < 128) hist[t] = 0;
    __syncthreads();
    const int start = bktBase[bk];
    const int cnt   = bktTotal[bk];
    for (int i = t; i < cnt; i += 256)
        atomicAdd(&hist[ebuf[start + i] >> 17], 1);
    __syncthreads();
    int v = (t < 128) ? hist[t] : 0;
    #pragma unroll
    for (int o = 1; o < 128; o <<= 1) {
        int add = (t < 128 && t >= o) ? hist[t - o] : 0;
        __syncthreads();
        if (t < 128) hist[t] += add;
        __syncthreads();
    }
    if (t < 128) {
        const int excl = hist[t] - v;
        cur[t] = excl;
        const int node = bk * 128 + t;
        if (node < N_NODES) offs[node] = start + excl;
    }
    if (bk == 0 && t == 0) offs[N_NODES] = N_EDGES;
    __syncthreads();
    for (int i = t; i < cnt; i += 256) {
        const unsigned int e = ebuf[start + i];
        const int dl = e >> 17;
        const int p = atomicAdd(&cur[dl], 1);
        csr_src[start + p] = (int)(e & 0x1FFFF);
    }
}

// ---------------------------------------------------------------------------
// Gather-aggregate fused with GIN self-term (bf16 rows, fp32 accum):
//   h_in[i] = bf16( (1+eps)*x[i] + sum_{j in N(i)} x[j] )
// 8 nodes/block, 32 threads/node; 32-edge tiles, 4 independent acc chains.
// ---------------------------------------------------------------------------
__global__ __launch_bounds__(256) void gather_kernel(
    const ushort* __restrict__ xb,
    const float* __restrict__ eps_p,
    const int* __restrict__ offs,
    const int* __restrict__ csr_src,
    ushort* __restrict__ h_in) {
    const int node = blockIdx.x * 8 + (threadIdx.x >> 5);
    const int l32 = threadIdx.x & 31;
    const int c = l32 * 4;
    const int beg = offs[node];
    const int end = offs[node + 1];

    float4 A0 = {0.f,0.f,0.f,0.f}, A1 = {0.f,0.f,0.f,0.f};
    float4 A2 = {0.f,0.f,0.f,0.f}, A3 = {0.f,0.f,0.f,0.f};

    for (int base = beg; base < end; base += 32) {
        const int nn = min(32, end - base);
        const int sidx = csr_src[base + min(l32, nn - 1)];
        int i = 0;
        for (; i + 4 <= nn; i += 4) {
            const int s0 = __shfl(sidx, i + 0, 32);
            const int s1 = __shfl(sidx, i + 1, 32);
            const int s2 = __shfl(sidx, i + 2, 32);
            const int s3 = __shfl(sidx, i + 3, 32);
            ushort4 v0 = *reinterpret_cast<const ushort4*>(xb + (size_t)s0 * IN_CH + c);
            ushort4 v1 = *reinterpret_cast<const ushort4*>(xb + (size_t)s1 * IN_CH + c);
            ushort4 v2 = *reinterpret_cast<const ushort4*>(xb + (size_t)s2 * IN_CH + c);
            ushort4 v3 = *reinterpret_cast<const ushort4*>(xb + (size_t)s3 * IN_CH + c);
            A0.x += b2f(v0.x); A0.y += b2f(v0.y); A0.z += b2f(v0.z); A0.w += b2f(v0.w);
            A1.x += b2f(v1.x); A1.y += b2f(v1.y); A1.z += b2f(v1.z); A1.w += b2f(v1.w);
            A2.x += b2f(v2.x); A2.y += b2f(v2.y); A2.z += b2f(v2.z); A2.w += b2f(v2.w);
            A3.x += b2f(v3.x); A3.y += b2f(v3.y); A3.z += b2f(v3.z); A3.w += b2f(v3.w);
        }
        for (; i < nn; ++i) {
            const int s = __shfl(sidx, i, 32);
            ushort4 v = *reinterpret_cast<const ushort4*>(xb + (size_t)s * IN_CH + c);
            A0.x += b2f(v.x); A0.y += b2f(v.y); A0.z += b2f(v.z); A0.w += b2f(v.w);
        }
    }

    const float a0 = A0.x + A1.x + A2.x + A3.x;
    const float a1 = A0.y + A1.y + A2.y + A3.y;
    const float a2 = A0.z + A1.z + A2.z + A3.z;
    const float a3 = A0.w + A1.w + A2.w + A3.w;

    const float scale = 1.0f + eps_p[0];
    ushort4 sv = *reinterpret_cast<const ushort4*>(xb + (size_t)node * IN_CH + c);
    ushort4 o;
    o.x = f2b(scale * b2f(sv.x) + a0);
    o.y = f2b(scale * b2f(sv.y) + a1);
    o.z = f2b(scale * b2f(sv.z) + a2);
    o.w = f2b(scale * b2f(sv.w) + a3);
    *reinterpret_cast<ushort4*>(h_in + (size_t)node * IN_CH + c) = o;
}

// ---------------------------------------------------------------------------
// Fused MLP (MFMA): out = log_softmax(relu(relu(h_in@W1+b1)@W2+b2))
// 512 thr = 8 waves x 16 rows = 128 rows/block. W1T staged into a 64 KB
// XOR-swizzled LDS buffer (re-staged with W2T after phase 1) so all
// B-fragment reads are conflict-free ds_read_b128 instead of per-wave L2
// round trips. h1 parked in per-wave padded LDS tiles (wave-private, no
// cross-wave barrier needed for it).
// Swizzle: half_in_row ^= (row&7)<<3  (bijective, 16B-aligned preserved;
// spreads the 16 lr-lanes of a B-read across 8 slots -> 2 lanes/bank = free).
// ---------------------------------------------------------------------------
#define H1_LD 264          // padded h1 row stride in halves
__global__ __launch_bounds__(512) void mlp_fused(
    const ushort* __restrict__ h_in,
    const ushort* __restrict__ W1T,
    const ushort* __restrict__ W2T,
    const float* __restrict__ b1,
    const float* __restrict__ b2,
    float* __restrict__ out) {
    __shared__ ushort wbuf[32768];            // 64 KB weights (W1T, then W2T)
    __shared__ ushort h1s[8][16 * H1_LD];     // 67.6 KB h1 tiles
    const int t    = threadIdx.x;
    const int w    = t >> 6;
    const int lane = t & 63;
    const int lr   = lane & 15;
    const int lk   = lane >> 4;
    const int row0 = blockIdx.x * 128 + w * 16;
    const int arow = row0 + lr;
    const int arc  = arow < N_NODES ? arow : N_NODES - 1;
    ushort* tile = h1s[w];
    const int sw = (lr & 7) << 3;             // read-side swizzle (halves)

    // ---- stage W1T (rows of 128 halves, swizzled); 64 halves/thread ----
    {
        const ushort* gw = W1T + t * 64;
        const int row = t >> 1;
        const int s = (row & 7) << 3;
        ushort* dstp = wbuf + row * 128;
        #pragma unroll
        for (int j = 0; j < 8; ++j) {
            short8 v = *reinterpret_cast<const short8*>(gw + j * 8);
            const int col = (t & 1) * 64 + j * 8;
            *reinterpret_cast<short8*>(dstp + (col ^ s)) = v;
        }
    }

    // A-frags for phase 1 (global h_in, L2-resident)
    short8 a[4];
    const ushort* ap = h_in + (size_t)arc * IN_CH + lk * 8;
    #pragma unroll
    for (int kk = 0; kk < 4; ++kk)
        a[kk] = *reinterpret_cast<const short8*>(ap + kk * 32);

    __syncthreads();

    // ---- phase 1: h1 = relu(h_in @ W1 + b1), 16 rows x 256 cols ----
    #pragma unroll
    for (int ct = 0; ct < 16; ++ct) {
        const ushort* bp = wbuf + (ct * 16 + lr) * 128;
        f32x4 acc = (f32x4){0.f, 0.f, 0.f, 0.f};
        #pragma unroll
        for (int kk = 0; kk < 4; ++kk) {
            short8 b = *reinterpret_cast<const short8*>(bp + ((lk * 8 + kk * 32) ^ sw));
            acc = __builtin_amdgcn_mfma_f32_16x16x32_bf16(a[kk], b, acc, 0, 0, 0);
        }
        const float bb = b1[ct * 16 + lr];
        #pragma unroll
        for (int r = 0; r < 4; ++r) {
            float v = fmaxf(acc[r] + bb, 0.0f);
            tile[(lk * 4 + r) * H1_LD + ct * 16 + lr] = f2b(v);
        }
    }

    __syncthreads();   // all waves done reading W1 from wbuf

    // ---- stage W2T (rows of 256 halves, swizzled) ----
    {
        const ushort* gw = W2T + t * 64;
        const int row = t >> 2;
        const int s = (row & 7) << 3;
        ushort* dstp = wbuf + row * 256;
        #pragma unroll
        for (int j = 0; j < 8; ++j) {
            short8 v = *reinterpret_cast<const short8*>(gw + j * 8);
            const int col = (t & 3) * 64 + j * 8;
            *reinterpret_cast<short8*>(dstp + (col ^ s)) = v;
        }
    }

    // A2-frags from own (wave-private) tile — safe before the barrier
    short8 a2[8];
    #pragma unroll
    for (int kk = 0; kk < 8; ++kk)
        a2[kk] = *reinterpret_cast<const short8*>(tile + lr * H1_LD + lk * 8 + kk * 32);

    __syncthreads();   // W2 staged

    // ---- phase 2: out = lsm(relu(h1 @ W2 + b2)), 16 rows x 128 cols ----
    f32x4 acc2[8];
    #pragma unroll
    for (int ct = 0; ct < 8; ++ct) acc2[ct] = (f32x4){0.f, 0.f, 0.f, 0.f};

    #pragma unroll
    for (int ct = 0; ct < 8; ++ct) {
        const ushort* bp = wbuf + (ct * 16 + lr) * 256;
        #pragma unroll
        for (int kk = 0; kk < 8; ++kk) {
            short8 b = *reinterpret_cast<const short8*>(bp + ((lk * 8 + kk * 32) ^ sw));
            acc2[ct] = __builtin_amdgcn_mfma_f32_16x16x32_bf16(a2[kk], b, acc2[ct], 0, 0, 0);
        }
    }

    float bias[8];
    #pragma unroll
    for (int ct = 0; ct < 8; ++ct) bias[ct] = b2[ct * 16 + lr];

    const int orow0 = row0 + lk * 4;
    #pragma unroll
    for (int r = 0; r < 4; ++r) {
        float v[8];
        float m = -1e30f;
        #pragma unroll
        for (int ct = 0; ct < 8; ++ct) {
            v[ct] = fmaxf(acc2[ct][r] + bias[ct], 0.0f);
            m = fmaxf(m, v[ct]);
        }
        #pragma unroll
        for (int o = 1; o < 16; o <<= 1) m = fmaxf(m, __shfl_xor(m, o));
        float s = 0.0f;
        #pragma unroll
        for (int ct = 0; ct < 8; ++ct) s += __expf(v[ct] - m);
        #pragma unroll
        for (int o = 1; o < 16; o <<= 1) s += __shfl_xor(s, o);
        const float lse = m + __logf(s);
        const int orow = orow0 + r;
        if (orow < N_NODES) {
            #pragma unroll
            for (int ct = 0; ct < 8; ++ct)
                out[(size_t)orow * OUT_CH + ct * 16 + lr] = v[ct] - lse;
        }
    }
}

extern "C" void kernel_launch(void* const* d_in, const int* in_sizes, int n_in,
                              void* d_out, int out_size, void* d_ws, size_t ws_size,
                              hipStream_t stream) {
    const float* x    = (const float*)d_in[0];
    const int*   ei   = (const int*)d_in[1];
    const float* W1   = (const float*)d_in[2];
    const float* b1   = (const float*)d_in[3];
    const float* W2   = (const float*)d_in[4];
    const float* b2   = (const float*)d_in[5];
    const float* eps  = (const float*)d_in[6];
    float* out = (float*)d_out;

    // workspace layout
    ushort* xb   = (ushort*)d_ws;                          // 12.8M ushort
    ushort* h_in = xb + (size_t)N_NODES * IN_CH;           // 12.8M
    ushort* W1T  = h_in + (size_t)N_NODES * IN_CH;         // 32768
    ushort* W2T  = W1T + IN_CH * HID_CH;                   // 32768
    int* histT      = (int*)(W2T + HID_CH * OUT_CH);       // NBK*256
    int* blockBaseP = histT + NBK * BIN_BLOCKS;            // NBK*256
    int* bktTotal   = blockBaseP + NBK * BIN_BLOCKS;       // NBK
    int* bktBase    = bktTotal + NBK;                      // NBK
    int* offs       = bktBase + NBK;                       // N_NODES+1
    unsigned int* ebuf = (unsigned int*)(offs + N_NODES + 2); // 1.6M
    int* csr_src    = (int*)(ebuf + N_EDGES);              // 1.6M

    const int* src = ei;
    const int* dst = ei + N_EDGES;

    prep_kernel<<<PREP_X_BLOCKS + PREP_W1_BLOCKS + PREP_W2_BLOCKS, 256, 0, stream>>>(
        x, W1, W2, xb, W1T, W2T);
    ghist_kernel<<<BIN_BLOCKS, 256, 0, stream>>>(dst, histT);
    scanA_kernel<<<NBK, 256, 0, stream>>>(histT, blockBaseP, bktTotal);
    scanB_kernel<<<1, 1024, 0, stream>>>(bktTotal, bktBase);
    bin_kernel<<<BIN_BLOCKS, 256, 0, stream>>>(src, dst, blockBaseP, bktBase, ebuf);
    group_kernel<<<NBK, 256, 0, stream>>>(ebuf, bktBase, bktTotal, csr_src, offs);
    gather_kernel<<<N_NODES / 8, 256, 0, stream>>>(xb, eps, offs, csr_src, h_in);

    mlp_fused<<<(N_NODES + 127) / 128, 512, 0, stream>>>(h_in, W1T, W2T, b1, b2, out);
}